// Round 2
// baseline (635.373 us; speedup 1.0000x reference)
//
#include <hip/hip_runtime.h>
#include <math.h>

// Problem constants
// B=64, N=384, NFEAT=16, E=3, NHID=NOUT=128, ST_HID=64, ST_OUT=16
#define ROWS 24576            // B*N
#define ADJ_BE (384*384)      // per (b,e) adj matrix elems

// ---------------- kernel 1: h0 = x @ emb_w^T ----------------
__global__ __launch_bounds__(256) void k_embed(const float* __restrict__ x,
        const float* __restrict__ emb_w, float* __restrict__ h0) {
    __shared__ float w[16][16];
    int t = threadIdx.x;
    w[t >> 4][t & 15] = emb_w[t];          // 256 elems exactly
    __syncthreads();
    int idx = blockIdx.x * 256 + t;        // element index row*16+d
    int row = idx >> 4, d = idx & 15;
    const float* xr = x + (size_t)row * 16;
    float acc = 0.f;
#pragma unroll
    for (int k = 0; k < 16; ++k) acc = fmaf(xr[k], w[d][k], acc);
    h0[idx] = acc;
}

// ---------------- kernel 2: T[b,e] = adj[b,e] @ h0[b]  (128x16 tile, K=384) ----------------
__global__ __launch_bounds__(256) void k_adj_h0(const float* __restrict__ adj,
        const float* __restrict__ h0, float* __restrict__ T1) {
    int mt = blockIdx.x, e = blockIdx.y, b = blockIdx.z;
    const float* A = adj + (size_t)(b * 3 + e) * ADJ_BE + (size_t)mt * 128 * 384;
    const float* H = h0 + (size_t)b * 384 * 16;
    __shared__ float aT[32][132];   // [k][m] transposed, f4-aligned pad
    __shared__ float hB[32][16];    // [k][h]
    int t = threadIdx.x;
    int tx = t & 3;                 // cols 4*tx .. 4*tx+3
    int ty = t >> 2;                // rows 2*ty, 2*ty+1   (0..63)
    float acc[2][4] = {};
    for (int k0 = 0; k0 < 384; k0 += 32) {
        __syncthreads();
#pragma unroll
        for (int p = 0; p < 4; ++p) {          // adj tile 128x32 -> transposed (1024 f4)
            int idx = t + p * 256;
            int r = idx >> 3, q = idx & 7;
            float4 v = *(const float4*)(A + (size_t)r * 384 + k0 + q * 4);
            aT[q*4+0][r] = v.x; aT[q*4+1][r] = v.y; aT[q*4+2][r] = v.z; aT[q*4+3][r] = v.w;
        }
        if (t < 128) {                         // h0 tile 32x16 (128 f4)
            int r = t >> 2, q = t & 3;
            *(float4*)&hB[r][q * 4] = *(const float4*)(H + (size_t)(k0 + r) * 16 + q * 4);
        }
        __syncthreads();
#pragma unroll
        for (int k = 0; k < 32; ++k) {
            float2 av = *(const float2*)&aT[k][2 * ty];
            float4 bv = *(const float4*)&hB[k][4 * tx];
            acc[0][0] = fmaf(av.x, bv.x, acc[0][0]);
            acc[0][1] = fmaf(av.x, bv.y, acc[0][1]);
            acc[0][2] = fmaf(av.x, bv.z, acc[0][2]);
            acc[0][3] = fmaf(av.x, bv.w, acc[0][3]);
            acc[1][0] = fmaf(av.y, bv.x, acc[1][0]);
            acc[1][1] = fmaf(av.y, bv.y, acc[1][1]);
            acc[1][2] = fmaf(av.y, bv.z, acc[1][2]);
            acc[1][3] = fmaf(av.y, bv.w, acc[1][3]);
        }
    }
    float* Tp = T1 + (size_t)(b * 3 + e) * (384 * 16) + (size_t)(mt * 128) * 16;
#pragma unroll
    for (int i = 0; i < 2; ++i) {
        float4 v = make_float4(acc[i][0], acc[i][1], acc[i][2], acc[i][3]);
        *(float4*)&Tp[(2 * ty + i) * 16 + 4 * tx] = v;
    }
}

// ---------------- kernel 3: h1 = sum_e relu(T[b,e] @ W1[e])  (K=16) ----------------
__global__ __launch_bounds__(256) void k_l1s2(const float* __restrict__ T1,
        const float* __restrict__ W1, float* __restrict__ h1) {
    __shared__ float wL[3][16][128];
    __shared__ float tL[3][64][17];
    int t = threadIdx.x;
    int rt = blockIdx.x;             // 64-row tile of flattened (b*384+m)
    int b = rt / 6, m0 = (rt % 6) * 64;
#pragma unroll
    for (int p = 0; p < 6; ++p) {    // W1: 3*16*128 floats = 1536 f4
        int idx = t + p * 256;
        float4 v = *(const float4*)(W1 + (size_t)idx * 4);
        int e = idx / 512, rem = idx % 512;
        int d = rem >> 5, q = rem & 31;
        *(float4*)&wL[e][d][q * 4] = v;
    }
#pragma unroll
    for (int p = 0; p < 3; ++p) {    // T tiles: 3*64*16 = 768 f4
        int idx = t + p * 256;
        int e = idx >> 8, rem = idx & 255;
        int r = rem >> 2, q = rem & 3;
        float4 v = *(const float4*)(T1 + ((size_t)(b * 3 + e) * 384 + m0 + r) * 16 + q * 4);
        tL[e][r][q*4+0] = v.x; tL[e][r][q*4+1] = v.y; tL[e][r][q*4+2] = v.z; tL[e][r][q*4+3] = v.w;
    }
    __syncthreads();
    int tx = t & 31;                 // cols c = tx + 32j, j<4
    int ty = t >> 5;                 // rows r = ty + 8i, i<8
    float tot[8][4] = {};
#pragma unroll
    for (int e = 0; e < 3; ++e) {
        float acc[8][4] = {};
#pragma unroll
        for (int d = 0; d < 16; ++d) {
            float a[8], w[4];
#pragma unroll
            for (int i = 0; i < 8; ++i) a[i] = tL[e][ty + 8 * i][d];
#pragma unroll
            for (int j = 0; j < 4; ++j) w[j] = wL[e][d][tx + 32 * j];
#pragma unroll
            for (int i = 0; i < 8; ++i)
#pragma unroll
                for (int j = 0; j < 4; ++j)
                    acc[i][j] = fmaf(a[i], w[j], acc[i][j]);
        }
#pragma unroll
        for (int i = 0; i < 8; ++i)
#pragma unroll
            for (int j = 0; j < 4; ++j)
                tot[i][j] += fmaxf(acc[i][j], 0.f);
    }
    float* out = h1 + (size_t)rt * 64 * 128;
#pragma unroll
    for (int i = 0; i < 8; ++i)
#pragma unroll
        for (int j = 0; j < 4; ++j)
            out[(ty + 8 * i) * 128 + tx + 32 * j] = tot[i][j];
}

// ---------------- kernel 4: S[b,e] = h[b] @ W[e]  (64x128 tile, K=128) ----------------
__global__ __launch_bounds__(256) void k_support(const float* __restrict__ hin,
        const float* __restrict__ W, float* __restrict__ S) {
    int rt = blockIdx.x, e = blockIdx.y;
    int b = rt / 6, n0 = (rt % 6) * 64;
    const float* Hp = hin + (size_t)rt * 64 * 128;
    const float* Wp = W + (size_t)e * 128 * 128;
    float* Sp = S + ((size_t)(b * 3 + e) * 384 + n0) * 128;
    __shared__ float aT[32][68];    // [k][row]
    __shared__ float bT[32][132];   // [k][col]
    int t = threadIdx.x;
    int tx = t & 15;                // cols {4tx..4tx+3, 64+4tx..}
    int ty = t >> 4;                // rows 4ty..4ty+3
    float acc[4][8] = {};
    for (int k0 = 0; k0 < 128; k0 += 32) {
        __syncthreads();
#pragma unroll
        for (int p = 0; p < 2; ++p) {          // h tile 64x32 transposed (512 f4)
            int idx = t + p * 256;
            int r = idx >> 3, q = idx & 7;
            float4 v = *(const float4*)(Hp + (size_t)r * 128 + k0 + q * 4);
            aT[q*4+0][r] = v.x; aT[q*4+1][r] = v.y; aT[q*4+2][r] = v.z; aT[q*4+3][r] = v.w;
        }
#pragma unroll
        for (int p = 0; p < 4; ++p) {          // W tile 32x128 (1024 f4)
            int idx = t + p * 256;
            int r = idx >> 5, q = idx & 31;
            *(float4*)&bT[r][q * 4] = *(const float4*)(Wp + (size_t)(k0 + r) * 128 + q * 4);
        }
        __syncthreads();
#pragma unroll
        for (int k = 0; k < 32; ++k) {
            float4 av = *(const float4*)&aT[k][4 * ty];
            float4 b0 = *(const float4*)&bT[k][4 * tx];
            float4 b1 = *(const float4*)&bT[k][64 + 4 * tx];
            float a[4] = {av.x, av.y, av.z, av.w};
            float bb[8] = {b0.x, b0.y, b0.z, b0.w, b1.x, b1.y, b1.z, b1.w};
#pragma unroll
            for (int i = 0; i < 4; ++i)
#pragma unroll
                for (int j = 0; j < 8; ++j)
                    acc[i][j] = fmaf(a[i], bb[j], acc[i][j]);
        }
    }
#pragma unroll
    for (int i = 0; i < 4; ++i) {
        float* Or = Sp + (size_t)(4 * ty + i) * 128;
        *(float4*)&Or[4 * tx]      = make_float4(acc[i][0], acc[i][1], acc[i][2], acc[i][3]);
        *(float4*)&Or[64 + 4 * tx] = make_float4(acc[i][4], acc[i][5], acc[i][6], acc[i][7]);
    }
}

// ---------------- kernel 5: out[b] += relu?(adj[b,e] @ S[b,e])  (64x128 tile, K=384) ----------------
template <int RELU>
__global__ __launch_bounds__(256) void k_adj_gemm(const float* __restrict__ adj,
        const float* __restrict__ S, float* __restrict__ out) {
    int mt = blockIdx.x, e = blockIdx.y, b = blockIdx.z;
    const float* A = adj + (size_t)(b * 3 + e) * ADJ_BE + (size_t)mt * 64 * 384;
    const float* Bp = S + (size_t)(b * 3 + e) * 384 * 128;
    float* O = out + ((size_t)b * 384 + mt * 64) * 128;
    __shared__ float aT[32][68];    // [k][m]
    __shared__ float bT[32][132];   // [k][n]
    int t = threadIdx.x;
    int tx = t & 15;                // cols {4tx.., 64+4tx..}
    int ty = t >> 4;                // rows 4ty..4ty+3
    float acc[4][8] = {};
    for (int k0 = 0; k0 < 384; k0 += 32) {
        __syncthreads();
#pragma unroll
        for (int p = 0; p < 2; ++p) {          // adj tile 64x32 transposed (512 f4)
            int idx = t + p * 256;
            int r = idx >> 3, q = idx & 7;
            float4 v = *(const float4*)(A + (size_t)r * 384 + k0 + q * 4);
            aT[q*4+0][r] = v.x; aT[q*4+1][r] = v.y; aT[q*4+2][r] = v.z; aT[q*4+3][r] = v.w;
        }
#pragma unroll
        for (int p = 0; p < 4; ++p) {          // S tile 32x128 (1024 f4)
            int idx = t + p * 256;
            int r = idx >> 5, q = idx & 31;
            *(float4*)&bT[r][q * 4] = *(const float4*)(Bp + (size_t)(k0 + r) * 128 + q * 4);
        }
        __syncthreads();
#pragma unroll
        for (int k = 0; k < 32; ++k) {
            float4 av = *(const float4*)&aT[k][4 * ty];
            float4 b0 = *(const float4*)&bT[k][4 * tx];
            float4 b1 = *(const float4*)&bT[k][64 + 4 * tx];
            float a[4] = {av.x, av.y, av.z, av.w};
            float bb[8] = {b0.x, b0.y, b0.z, b0.w, b1.x, b1.y, b1.z, b1.w};
#pragma unroll
            for (int i = 0; i < 4; ++i)
#pragma unroll
                for (int j = 0; j < 8; ++j)
                    acc[i][j] = fmaf(a[i], bb[j], acc[i][j]);
        }
    }
#pragma unroll
    for (int i = 0; i < 4; ++i) {
        float* Or = O + (size_t)(4 * ty + i) * 128;
#pragma unroll
        for (int j = 0; j < 4; ++j) {
            float v0 = RELU ? fmaxf(acc[i][j], 0.f) : acc[i][j];
            atomicAdd(Or + 4 * tx + j, v0);
        }
#pragma unroll
        for (int j = 0; j < 4; ++j) {
            float v1 = RELU ? fmaxf(acc[i][4 + j], 0.f) : acc[i][4 + j];
            atomicAdd(Or + 64 + 4 * tx + j, v1);
        }
    }
}

// ---------------- zero helper ----------------
__global__ void k_zero(float* __restrict__ p, int n4) {
    int i = blockIdx.x * blockDim.x + threadIdx.x;
    if (i < n4) ((float4*)p)[i] = float4{0.f, 0.f, 0.f, 0.f};
}

// ---------------- kernel 6: fused head ----------------
__global__ __launch_bounds__(256) void k_head(const float* __restrict__ h3,
        const float* __restrict__ st_w1, const float* __restrict__ st_b1,
        const float* __restrict__ st_w2, const float* __restrict__ st_b2,
        const float* __restrict__ rescale_w, float* __restrict__ out) {
    __shared__ float hL[64][132];
    __shared__ float w1L[64][132];
    __shared__ float ytL[64][68];
    __shared__ float w2L[32][68];
    __shared__ float b1L[64], b2L[32];
    int t = threadIdx.x;
    int r0 = blockIdx.x * 64;
#pragma unroll
    for (int p = 0; p < 8; ++p) {   // h rows 64x128 = 2048 f4
        int idx = t + p * 256;
        int r = idx >> 5, q = idx & 31;
        *(float4*)&hL[r][q * 4] = *(const float4*)(h3 + (size_t)(r0 + r) * 128 + q * 4);
    }
#pragma unroll
    for (int p = 0; p < 8; ++p) {   // w1 64x128
        int idx = t + p * 256;
        int r = idx >> 5, q = idx & 31;
        *(float4*)&w1L[r][q * 4] = *(const float4*)(st_w1 + (size_t)r * 128 + q * 4);
    }
#pragma unroll
    for (int p = 0; p < 2; ++p) {   // w2 32x64 = 512 f4
        int idx = t + p * 256;
        int r = idx >> 4, q = idx & 15;
        *(float4*)&w2L[r][q * 4] = *(const float4*)(st_w2 + (size_t)r * 64 + q * 4);
    }
    if (t < 64) b1L[t] = st_b1[t];
    else if (t < 96) b2L[t - 64] = st_b2[t - 64];
    __syncthreads();
    // phase 1: y = h @ w1^T + b1, tanh
    int tx = t & 15, ty = t >> 4;
    float acc[4][4] = {};
    for (int d = 0; d < 128; ++d) {
        float a[4], w[4];
#pragma unroll
        for (int i = 0; i < 4; ++i) a[i] = hL[ty + 16 * i][d];
#pragma unroll
        for (int j = 0; j < 4; ++j) w[j] = w1L[tx + 16 * j][d];
#pragma unroll
        for (int i = 0; i < 4; ++i)
#pragma unroll
            for (int j = 0; j < 4; ++j)
                acc[i][j] = fmaf(a[i], w[j], acc[i][j]);
    }
#pragma unroll
    for (int i = 0; i < 4; ++i)
#pragma unroll
        for (int j = 0; j < 4; ++j)
            ytL[ty + 16 * i][tx + 16 * j] = tanhf(acc[i][j] + b1L[tx + 16 * j]);
    __syncthreads();
    // phase 2: z = yt @ w2^T + b2; split into s (tanh*exp(rescale)) and t
    int tx8 = t & 7, ty32 = t >> 3;
    float acc2[2][4] = {};
    for (int d = 0; d < 64; ++d) {
        float a[2], w[4];
#pragma unroll
        for (int i = 0; i < 2; ++i) a[i] = ytL[ty32 + 32 * i][d];
#pragma unroll
        for (int j = 0; j < 4; ++j) w[j] = w2L[tx8 + 8 * j][d];
#pragma unroll
        for (int i = 0; i < 2; ++i)
#pragma unroll
            for (int j = 0; j < 4; ++j)
                acc2[i][j] = fmaf(a[i], w[j], acc2[i][j]);
    }
    float er = expf(rescale_w[0]);
#pragma unroll
    for (int i = 0; i < 2; ++i) {
        int r = r0 + ty32 + 32 * i;
#pragma unroll
        for (int j = 0; j < 4; ++j) {
            int c = tx8 + 8 * j;
            float z = acc2[i][j] + b2L[c];
            if (c < 16) out[(size_t)r * 16 + c] = er * tanhf(z);
            else        out[(size_t)(ROWS + r) * 16 + (c - 16)] = z;
        }
    }
}

extern "C" void kernel_launch(void* const* d_in, const int* in_sizes, int n_in,
                              void* d_out, int out_size, void* d_ws, size_t ws_size,
                              hipStream_t stream) {
    const float* x     = (const float*)d_in[0];
    const float* adj   = (const float*)d_in[1];
    const float* emb_w = (const float*)d_in[2];
    const float* gc1   = (const float*)d_in[3];
    const float* gc2   = (const float*)d_in[4];
    const float* gc3   = (const float*)d_in[5];
    const float* st_w1 = (const float*)d_in[6];
    const float* st_b1 = (const float*)d_in[7];
    const float* st_w2 = (const float*)d_in[8];
    const float* st_b2 = (const float*)d_in[9];
    const float* resc  = (const float*)d_in[10];
    float* out = (float*)d_out;
    float* ws  = (float*)d_ws;

    // workspace layout (floats): total ~69.2 MB
    float* h0 = ws;                    // 393216
    float* T1 = h0 + 393216;           // 1179648
    float* hA = T1 + 1179648;          // 3145728 (h1, later h3)
    float* S  = hA + 3145728;          // 9437184
    float* hB = S  + 9437184;          // 3145728 (h2)

    // embed
    k_embed<<<1536, 256, 0, stream>>>(x, emb_w, h0);
    // layer 1 (reassociated): T = adj@h0, h1 = sum_e relu(T@W1)
    k_adj_h0<<<dim3(3, 3, 64), 256, 0, stream>>>(adj, h0, T1);
    k_l1s2<<<384, 256, 0, stream>>>(T1, gc1, hA);
    // layer 2
    k_support<<<dim3(384, 3), 256, 0, stream>>>(hA, gc2, S);
    k_zero<<<3072, 256, 0, stream>>>(hB, 786432);
    k_adj_gemm<1><<<dim3(6, 3, 64), 256, 0, stream>>>(adj, S, hB);
    // layer 3 (no relu)
    k_support<<<dim3(384, 3), 256, 0, stream>>>(hB, gc3, S);
    k_zero<<<3072, 256, 0, stream>>>(hA, 786432);
    k_adj_gemm<0><<<dim3(6, 3, 64), 256, 0, stream>>>(adj, S, hA);
    // head
    k_head<<<384, 256, 0, stream>>>(hA, st_w1, st_b1, st_w2, st_b2, resc, out);
}

// Round 3
// 510.891 us; speedup vs baseline: 1.2437x; 1.2437x over previous
//
#include <hip/hip_runtime.h>
#include <math.h>

// Problem constants
// B=64, N=384, NFEAT=16, E=3, NHID=NOUT=128, ST_HID=64, ST_OUT=16
#define ROWS 24576            // B*N
#define ADJ_BE (384*384)      // per (b,e) adj matrix elems

// ---------------- kernel 1: fused embed + T[b,e] = adj[b,e] @ (x[b]@emb^T) ----------------
// 192-row tile, grid (2 mt, 3 e, 64 b), 256 threads.
__global__ __launch_bounds__(256) void k_embed_adj(const float* __restrict__ x,
        const float* __restrict__ emb_w, const float* __restrict__ adj,
        float* __restrict__ T1) {
    __shared__ float h0L[384][16];     // 24 KB, full h0[b]
    __shared__ float aT[32][196];      // 24.5 KB, [k][m] transposed adj tile
    int t = threadIdx.x;
    int mt = blockIdx.x, e = blockIdx.y, b = blockIdx.z;
    // phase 0: stage emb into aT scratch, compute h0L = x[b] @ emb^T (redundant per e — cheap)
    float* embL = &aT[0][0];
    if (t < 64) *(float4*)&embL[4 * t] = *(const float4*)(emb_w + 4 * t);
    __syncthreads();
    const float* xb = x + (size_t)b * 384 * 16;
    for (int rr = t; rr < 384; rr += 256) {
        float xr[16];
        *(float4*)&xr[0]  = *(const float4*)(xb + rr * 16);
        *(float4*)&xr[4]  = *(const float4*)(xb + rr * 16 + 4);
        *(float4*)&xr[8]  = *(const float4*)(xb + rr * 16 + 8);
        *(float4*)&xr[12] = *(const float4*)(xb + rr * 16 + 12);
        float o[16];
#pragma unroll
        for (int d = 0; d < 16; ++d) {
            float acc = 0.f;
#pragma unroll
            for (int k = 0; k < 16; ++k) acc = fmaf(xr[k], embL[d * 16 + k], acc);
            o[d] = acc;
        }
        *(float4*)&h0L[rr][0]  = *(float4*)&o[0];
        *(float4*)&h0L[rr][4]  = *(float4*)&o[4];
        *(float4*)&h0L[rr][8]  = *(float4*)&o[8];
        *(float4*)&h0L[rr][12] = *(float4*)&o[12];
    }
    // K-loop: T tile (192x16) = adj tile (192x384) @ h0 (384x16)
    const float* A = adj + (size_t)(b * 3 + e) * ADJ_BE + (size_t)mt * 192 * 384;
    int tc = t & 3, ty = t >> 2;       // rows {2ty,2ty+1,128+ty}, cols 4tc..4tc+3
    float acc[3][4] = {};
    for (int k0 = 0; k0 < 384; k0 += 32) {
        __syncthreads();
#pragma unroll
        for (int p = 0; p < 6; ++p) {  // 192x32 floats = 1536 f4, transposed scatter
            int idx = t + p * 256;
            int r = idx >> 3, q = idx & 7;
            float4 v = *(const float4*)(A + (size_t)r * 384 + k0 + q * 4);
            aT[q*4+0][r] = v.x; aT[q*4+1][r] = v.y; aT[q*4+2][r] = v.z; aT[q*4+3][r] = v.w;
        }
        __syncthreads();
#pragma unroll
        for (int k = 0; k < 32; ++k) {
            float2 a01 = *(const float2*)&aT[k][2 * ty];
            float a2 = aT[k][128 + ty];
            float4 bv = *(const float4*)&h0L[k0 + k][4 * tc];
            float bb[4] = {bv.x, bv.y, bv.z, bv.w};
#pragma unroll
            for (int j = 0; j < 4; ++j) {
                acc[0][j] = fmaf(a01.x, bb[j], acc[0][j]);
                acc[1][j] = fmaf(a01.y, bb[j], acc[1][j]);
                acc[2][j] = fmaf(a2,    bb[j], acc[2][j]);
            }
        }
    }
    float* Tp = T1 + (size_t)(b * 3 + e) * (384 * 16) + (size_t)(mt * 192) * 16;
    *(float4*)&Tp[(2 * ty) * 16 + 4 * tc]     = make_float4(acc[0][0], acc[0][1], acc[0][2], acc[0][3]);
    *(float4*)&Tp[(2 * ty + 1) * 16 + 4 * tc] = make_float4(acc[1][0], acc[1][1], acc[1][2], acc[1][3]);
    *(float4*)&Tp[(128 + ty) * 16 + 4 * tc]   = make_float4(acc[2][0], acc[2][1], acc[2][2], acc[2][3]);
}

// ---------------- kernel 3: h1 = sum_e relu(T[b,e] @ W1[e])  (K=16) ----------------
__global__ __launch_bounds__(256) void k_l1s2(const float* __restrict__ T1,
        const float* __restrict__ W1, float* __restrict__ h1) {
    __shared__ float wL[3][16][128];
    __shared__ float tL[3][64][17];
    int t = threadIdx.x;
    int rt = blockIdx.x;             // 64-row tile of flattened (b*384+m)
    int b = rt / 6, m0 = (rt % 6) * 64;
#pragma unroll
    for (int p = 0; p < 6; ++p) {    // W1: 3*16*128 floats = 1536 f4
        int idx = t + p * 256;
        float4 v = *(const float4*)(W1 + (size_t)idx * 4);
        int e = idx / 512, rem = idx % 512;
        int d = rem >> 5, q = rem & 31;
        *(float4*)&wL[e][d][q * 4] = v;
    }
#pragma unroll
    for (int p = 0; p < 3; ++p) {    // T tiles: 3*64*16 = 768 f4
        int idx = t + p * 256;
        int e = idx >> 8, rem = idx & 255;
        int r = rem >> 2, q = rem & 3;
        float4 v = *(const float4*)(T1 + ((size_t)(b * 3 + e) * 384 + m0 + r) * 16 + q * 4);
        tL[e][r][q*4+0] = v.x; tL[e][r][q*4+1] = v.y; tL[e][r][q*4+2] = v.z; tL[e][r][q*4+3] = v.w;
    }
    __syncthreads();
    int tx = t & 31;                 // cols c = tx + 32j, j<4
    int ty = t >> 5;                 // rows r = ty + 8i, i<8
    float tot[8][4] = {};
#pragma unroll
    for (int e = 0; e < 3; ++e) {
        float acc[8][4] = {};
#pragma unroll
        for (int d = 0; d < 16; ++d) {
            float a[8], w[4];
#pragma unroll
            for (int i = 0; i < 8; ++i) a[i] = tL[e][ty + 8 * i][d];
#pragma unroll
            for (int j = 0; j < 4; ++j) w[j] = wL[e][d][tx + 32 * j];
#pragma unroll
            for (int i = 0; i < 8; ++i)
#pragma unroll
                for (int j = 0; j < 4; ++j)
                    acc[i][j] = fmaf(a[i], w[j], acc[i][j]);
        }
#pragma unroll
        for (int i = 0; i < 8; ++i)
#pragma unroll
            for (int j = 0; j < 4; ++j)
                tot[i][j] += fmaxf(acc[i][j], 0.f);
    }
    float* out = h1 + (size_t)rt * 64 * 128;
#pragma unroll
    for (int i = 0; i < 8; ++i)
#pragma unroll
        for (int j = 0; j < 4; ++j)
            out[(ty + 8 * i) * 128 + tx + 32 * j] = tot[i][j];
}

// ---------------- kernel 4: S[b,e] = h[b] @ W[e]  (64x128 tile, K=128) ----------------
__global__ __launch_bounds__(256) void k_support(const float* __restrict__ hin,
        const float* __restrict__ W, float* __restrict__ S) {
    int rt = blockIdx.x, e = blockIdx.y;
    int b = rt / 6, n0 = (rt % 6) * 64;
    const float* Hp = hin + (size_t)rt * 64 * 128;
    const float* Wp = W + (size_t)e * 128 * 128;
    float* Sp = S + ((size_t)(b * 3 + e) * 384 + n0) * 128;
    __shared__ float aT[32][68];    // [k][row]
    __shared__ float bT[32][132];   // [k][col]
    int t = threadIdx.x;
    int tx = t & 15;                // cols {4tx..4tx+3, 64+4tx..}
    int ty = t >> 4;                // rows 4ty..4ty+3
    float acc[4][8] = {};
    for (int k0 = 0; k0 < 128; k0 += 32) {
        __syncthreads();
#pragma unroll
        for (int p = 0; p < 2; ++p) {          // h tile 64x32 transposed (512 f4)
            int idx = t + p * 256;
            int r = idx >> 3, q = idx & 7;
            float4 v = *(const float4*)(Hp + (size_t)r * 128 + k0 + q * 4);
            aT[q*4+0][r] = v.x; aT[q*4+1][r] = v.y; aT[q*4+2][r] = v.z; aT[q*4+3][r] = v.w;
        }
#pragma unroll
        for (int p = 0; p < 4; ++p) {          // W tile 32x128 (1024 f4)
            int idx = t + p * 256;
            int r = idx >> 5, q = idx & 31;
            *(float4*)&bT[r][q * 4] = *(const float4*)(Wp + (size_t)(k0 + r) * 128 + q * 4);
        }
        __syncthreads();
#pragma unroll
        for (int k = 0; k < 32; ++k) {
            float4 av = *(const float4*)&aT[k][4 * ty];
            float4 b0 = *(const float4*)&bT[k][4 * tx];
            float4 b1 = *(const float4*)&bT[k][64 + 4 * tx];
            float a[4] = {av.x, av.y, av.z, av.w};
            float bb[8] = {b0.x, b0.y, b0.z, b0.w, b1.x, b1.y, b1.z, b1.w};
#pragma unroll
            for (int i = 0; i < 4; ++i)
#pragma unroll
                for (int j = 0; j < 8; ++j)
                    acc[i][j] = fmaf(a[i], bb[j], acc[i][j]);
        }
    }
#pragma unroll
    for (int i = 0; i < 4; ++i) {
        float* Or = Sp + (size_t)(4 * ty + i) * 128;
        *(float4*)&Or[4 * tx]      = make_float4(acc[i][0], acc[i][1], acc[i][2], acc[i][3]);
        *(float4*)&Or[64 + 4 * tx] = make_float4(acc[i][4], acc[i][5], acc[i][6], acc[i][7]);
    }
}

// ---------------- kernel 5: out[b] += relu?(adj[b,e] @ S[b,e])  (96x128 tile, K=384) ----------------
// grid (4 mt, 3 e, 64 b) = 768 blocks = exactly 3.0 blocks/CU.
template <int RELU>
__global__ __launch_bounds__(256) void k_adj_gemm(const float* __restrict__ adj,
        const float* __restrict__ S, float* __restrict__ out) {
    int mt = blockIdx.x, e = blockIdx.y, b = blockIdx.z;
    const float* A = adj + (size_t)(b * 3 + e) * ADJ_BE + (size_t)mt * 96 * 384;
    const float* Bp = S + (size_t)(b * 3 + e) * 384 * 128;
    float* O = out + ((size_t)b * 384 + mt * 96) * 128;
    __shared__ float aT[32][100];   // [k][m], pad 96->100 (b128-aligned)
    __shared__ float bT[32][128];   // [k][n], unpadded (stride-16 col reads are conflict-free)
    int t = threadIdx.x;
    int tx = t & 15;                // cols tx + 16j, j<8 (contiguous 16-lane groups)
    int ty = t >> 4;                // rows {4ty..4ty+3, 64+2ty, 65+2ty}
    float acc[6][8] = {};
    for (int k0 = 0; k0 < 384; k0 += 32) {
        __syncthreads();
#pragma unroll
        for (int p = 0; p < 3; ++p) {          // adj tile 96x32 transposed (768 f4)
            int idx = t + p * 256;
            int r = idx >> 3, q = idx & 7;
            float4 v = *(const float4*)(A + (size_t)r * 384 + k0 + q * 4);
            aT[q*4+0][r] = v.x; aT[q*4+1][r] = v.y; aT[q*4+2][r] = v.z; aT[q*4+3][r] = v.w;
        }
#pragma unroll
        for (int p = 0; p < 4; ++p) {          // S tile 32x128 (1024 f4)
            int idx = t + p * 256;
            int r = idx >> 5, q = idx & 31;
            *(float4*)&bT[r][q * 4] = *(const float4*)(Bp + (size_t)(k0 + r) * 128 + q * 4);
        }
        __syncthreads();
#pragma unroll
        for (int k = 0; k < 32; ++k) {
            float4 a0 = *(const float4*)&aT[k][4 * ty];
            float2 a1 = *(const float2*)&aT[k][64 + 2 * ty];
            float a[6] = {a0.x, a0.y, a0.z, a0.w, a1.x, a1.y};
            float bb[8];
#pragma unroll
            for (int j = 0; j < 8; ++j) bb[j] = bT[k][tx + 16 * j];
#pragma unroll
            for (int i = 0; i < 6; ++i)
#pragma unroll
                for (int j = 0; j < 8; ++j)
                    acc[i][j] = fmaf(a[i], bb[j], acc[i][j]);
        }
    }
    // epilogue: contiguous atomics (16 lanes span one 64B line per instr)
#pragma unroll
    for (int i = 0; i < 4; ++i) {
        float* Or = O + (size_t)(4 * ty + i) * 128;
#pragma unroll
        for (int j = 0; j < 8; ++j) {
            float v = RELU ? fmaxf(acc[i][j], 0.f) : acc[i][j];
            atomicAdd(Or + tx + 16 * j, v);
        }
    }
#pragma unroll
    for (int i = 0; i < 2; ++i) {
        float* Or = O + (size_t)(64 + 2 * ty + i) * 128;
#pragma unroll
        for (int j = 0; j < 8; ++j) {
            float v = RELU ? fmaxf(acc[4 + i][j], 0.f) : acc[4 + i][j];
            atomicAdd(Or + tx + 16 * j, v);
        }
    }
}

// ---------------- zero helper ----------------
__global__ void k_zero(float* __restrict__ p, int n4) {
    int i = blockIdx.x * blockDim.x + threadIdx.x;
    if (i < n4) ((float4*)p)[i] = float4{0.f, 0.f, 0.f, 0.f};
}

// ---------------- kernel 6: fused head ----------------
__global__ __launch_bounds__(256) void k_head(const float* __restrict__ h3,
        const float* __restrict__ st_w1, const float* __restrict__ st_b1,
        const float* __restrict__ st_w2, const float* __restrict__ st_b2,
        const float* __restrict__ rescale_w, float* __restrict__ out) {
    __shared__ float hL[64][132];
    __shared__ float w1L[64][132];
    __shared__ float ytL[64][68];
    __shared__ float w2L[32][68];
    __shared__ float b1L[64], b2L[32];
    int t = threadIdx.x;
    int r0 = blockIdx.x * 64;
#pragma unroll
    for (int p = 0; p < 8; ++p) {   // h rows 64x128 = 2048 f4
        int idx = t + p * 256;
        int r = idx >> 5, q = idx & 31;
        *(float4*)&hL[r][q * 4] = *(const float4*)(h3 + (size_t)(r0 + r) * 128 + q * 4);
    }
#pragma unroll
    for (int p = 0; p < 8; ++p) {   // w1 64x128
        int idx = t + p * 256;
        int r = idx >> 5, q = idx & 31;
        *(float4*)&w1L[r][q * 4] = *(const float4*)(st_w1 + (size_t)r * 128 + q * 4);
    }
#pragma unroll
    for (int p = 0; p < 2; ++p) {   // w2 32x64 = 512 f4
        int idx = t + p * 256;
        int r = idx >> 4, q = idx & 15;
        *(float4*)&w2L[r][q * 4] = *(const float4*)(st_w2 + (size_t)r * 64 + q * 4);
    }
    if (t < 64) b1L[t] = st_b1[t];
    else if (t < 96) b2L[t - 64] = st_b2[t - 64];
    __syncthreads();
    // phase 1: y = h @ w1^T + b1, tanh
    int tx = t & 15, ty = t >> 4;
    float acc[4][4] = {};
    for (int d = 0; d < 128; ++d) {
        float a[4], w[4];
#pragma unroll
        for (int i = 0; i < 4; ++i) a[i] = hL[ty + 16 * i][d];
#pragma unroll
        for (int j = 0; j < 4; ++j) w[j] = w1L[tx + 16 * j][d];
#pragma unroll
        for (int i = 0; i < 4; ++i)
#pragma unroll
            for (int j = 0; j < 4; ++j)
                acc[i][j] = fmaf(a[i], w[j], acc[i][j]);
    }
#pragma unroll
    for (int i = 0; i < 4; ++i)
#pragma unroll
        for (int j = 0; j < 4; ++j)
            ytL[ty + 16 * i][tx + 16 * j] = tanhf(acc[i][j] + b1L[tx + 16 * j]);
    __syncthreads();
    // phase 2: z = yt @ w2^T + b2; split into s (tanh*exp(rescale)) and t
    int tx8 = t & 7, ty32 = t >> 3;
    float acc2[2][4] = {};
    for (int d = 0; d < 64; ++d) {
        float a[2], w[4];
#pragma unroll
        for (int i = 0; i < 2; ++i) a[i] = ytL[ty32 + 32 * i][d];
#pragma unroll
        for (int j = 0; j < 4; ++j) w[j] = w2L[tx8 + 8 * j][d];
#pragma unroll
        for (int i = 0; i < 2; ++i)
#pragma unroll
            for (int j = 0; j < 4; ++j)
                acc2[i][j] = fmaf(a[i], w[j], acc2[i][j]);
    }
    float er = expf(rescale_w[0]);
#pragma unroll
    for (int i = 0; i < 2; ++i) {
        int r = r0 + ty32 + 32 * i;
#pragma unroll
        for (int j = 0; j < 4; ++j) {
            int c = tx8 + 8 * j;
            float z = acc2[i][j] + b2L[c];
            if (c < 16) out[(size_t)r * 16 + c] = er * tanhf(z);
            else        out[(size_t)(ROWS + r) * 16 + (c - 16)] = z;
        }
    }
}

extern "C" void kernel_launch(void* const* d_in, const int* in_sizes, int n_in,
                              void* d_out, int out_size, void* d_ws, size_t ws_size,
                              hipStream_t stream) {
    const float* x     = (const float*)d_in[0];
    const float* adj   = (const float*)d_in[1];
    const float* emb_w = (const float*)d_in[2];
    const float* gc1   = (const float*)d_in[3];
    const float* gc2   = (const float*)d_in[4];
    const float* gc3   = (const float*)d_in[5];
    const float* st_w1 = (const float*)d_in[6];
    const float* st_b1 = (const float*)d_in[7];
    const float* st_w2 = (const float*)d_in[8];
    const float* st_b2 = (const float*)d_in[9];
    const float* resc  = (const float*)d_in[10];
    float* out = (float*)d_out;
    float* ws  = (float*)d_ws;

    // workspace layout (floats): total ~67.6 MB
    float* T1 = ws;                    // 1179648
    float* hA = T1 + 1179648;          // 3145728 (h1, later h3)
    float* S  = hA + 3145728;          // 9437184
    float* hB = S  + 9437184;          // 3145728 (h2)

    // layer 1 (reassociated): T = adj@(x@emb^T), h1 = sum_e relu(T@W1)
    k_embed_adj<<<dim3(2, 3, 64), 256, 0, stream>>>(x, emb_w, adj, T1);
    k_l1s2<<<384, 256, 0, stream>>>(T1, gc1, hA);
    // layer 2
    k_support<<<dim3(384, 3), 256, 0, stream>>>(hA, gc2, S);
    k_zero<<<3072, 256, 0, stream>>>(hB, 786432);
    k_adj_gemm<1><<<dim3(4, 3, 64), 256, 0, stream>>>(adj, S, hB);
    // layer 3 (no relu)
    k_support<<<dim3(384, 3), 256, 0, stream>>>(hB, gc3, S);
    k_zero<<<3072, 256, 0, stream>>>(hA, 786432);
    k_adj_gemm<0><<<dim3(4, 3, 64), 256, 0, stream>>>(adj, S, hA);
    // head
    k_head<<<384, 256, 0, stream>>>(hA, st_w1, st_b1, st_w2, st_b2, resc, out);
}

// Round 5
// 456.547 us; speedup vs baseline: 1.3917x; 1.1190x over previous
//
#include <hip/hip_runtime.h>
#include <math.h>

// Problem constants
// B=64, N=384, NFEAT=16, E=3, NHID=NOUT=128, ST_HID=64, ST_OUT=16
#define ROWS 24576            // B*N
#define ADJ_BE (384*384)      // per (b,e) adj matrix elems

typedef _Float16 h4v __attribute__((ext_vector_type(4)));
typedef _Float16 h8v __attribute__((ext_vector_type(8)));
typedef float f32x4 __attribute__((ext_vector_type(4)));

#define SPLIT_SCALE 2048.0f
#define INV_SPLIT_SCALE (1.0f / 2048.0f)

// ---------------- kernel 1: fused embed + T[b,e] = adj[b,e] @ (x[b]@emb^T) ----------------
// 192-row tile, grid (2 mt, 3 e, 64 b), 256 threads.
__global__ __launch_bounds__(256) void k_embed_adj(const float* __restrict__ x,
        const float* __restrict__ emb_w, const float* __restrict__ adj,
        float* __restrict__ T1) {
    __shared__ float h0L[384][16];     // 24 KB, full h0[b]
    __shared__ float aT[32][196];      // 24.5 KB, [k][m] transposed adj tile
    int t = threadIdx.x;
    int mt = blockIdx.x, e = blockIdx.y, b = blockIdx.z;
    // phase 0: stage emb into aT scratch, compute h0L = x[b] @ emb^T (redundant per e — cheap)
    float* embL = &aT[0][0];
    if (t < 64) *(float4*)&embL[4 * t] = *(const float4*)(emb_w + 4 * t);
    __syncthreads();
    const float* xb = x + (size_t)b * 384 * 16;
    for (int rr = t; rr < 384; rr += 256) {
        float xr[16];
        *(float4*)&xr[0]  = *(const float4*)(xb + rr * 16);
        *(float4*)&xr[4]  = *(const float4*)(xb + rr * 16 + 4);
        *(float4*)&xr[8]  = *(const float4*)(xb + rr * 16 + 8);
        *(float4*)&xr[12] = *(const float4*)(xb + rr * 16 + 12);
        float o[16];
#pragma unroll
        for (int d = 0; d < 16; ++d) {
            float acc = 0.f;
#pragma unroll
            for (int k = 0; k < 16; ++k) acc = fmaf(xr[k], embL[d * 16 + k], acc);
            o[d] = acc;
        }
        *(float4*)&h0L[rr][0]  = *(float4*)&o[0];
        *(float4*)&h0L[rr][4]  = *(float4*)&o[4];
        *(float4*)&h0L[rr][8]  = *(float4*)&o[8];
        *(float4*)&h0L[rr][12] = *(float4*)&o[12];
    }
    // K-loop: T tile (192x16) = adj tile (192x384) @ h0 (384x16)
    const float* A = adj + (size_t)(b * 3 + e) * ADJ_BE + (size_t)mt * 192 * 384;
    int tc = t & 3, ty = t >> 2;       // rows {2ty,2ty+1,128+ty}, cols 4tc..4tc+3
    float acc[3][4] = {};
    for (int k0 = 0; k0 < 384; k0 += 32) {
        __syncthreads();
#pragma unroll
        for (int p = 0; p < 6; ++p) {  // 192x32 floats = 1536 f4, transposed scatter
            int idx = t + p * 256;
            int r = idx >> 3, q = idx & 7;
            float4 v = *(const float4*)(A + (size_t)r * 384 + k0 + q * 4);
            aT[q*4+0][r] = v.x; aT[q*4+1][r] = v.y; aT[q*4+2][r] = v.z; aT[q*4+3][r] = v.w;
        }
        __syncthreads();
#pragma unroll
        for (int k = 0; k < 32; ++k) {
            float2 a01 = *(const float2*)&aT[k][2 * ty];
            float a2 = aT[k][128 + ty];
            float4 bv = *(const float4*)&h0L[k0 + k][4 * tc];
            float bb[4] = {bv.x, bv.y, bv.z, bv.w};
#pragma unroll
            for (int j = 0; j < 4; ++j) {
                acc[0][j] = fmaf(a01.x, bb[j], acc[0][j]);
                acc[1][j] = fmaf(a01.y, bb[j], acc[1][j]);
                acc[2][j] = fmaf(a2,    bb[j], acc[2][j]);
            }
        }
    }
    float* Tp = T1 + (size_t)(b * 3 + e) * (384 * 16) + (size_t)(mt * 192) * 16;
    *(float4*)&Tp[(2 * ty) * 16 + 4 * tc]     = make_float4(acc[0][0], acc[0][1], acc[0][2], acc[0][3]);
    *(float4*)&Tp[(2 * ty + 1) * 16 + 4 * tc] = make_float4(acc[1][0], acc[1][1], acc[1][2], acc[1][3]);
    *(float4*)&Tp[(128 + ty) * 16 + 4 * tc]   = make_float4(acc[2][0], acc[2][1], acc[2][2], acc[2][3]);
}

// ---------------- kernel 2: h1 = sum_e relu(T[b,e] @ W1[e])  (K=16) ----------------
__global__ __launch_bounds__(256) void k_l1s2(const float* __restrict__ T1,
        const float* __restrict__ W1, float* __restrict__ h1) {
    __shared__ float wL[3][16][128];
    __shared__ float tL[3][64][17];
    int t = threadIdx.x;
    int rt = blockIdx.x;             // 64-row tile of flattened (b*384+m)
    int b = rt / 6, m0 = (rt % 6) * 64;
#pragma unroll
    for (int p = 0; p < 6; ++p) {    // W1: 3*16*128 floats = 1536 f4
        int idx = t + p * 256;
        float4 v = *(const float4*)(W1 + (size_t)idx * 4);
        int e = idx / 512, rem = idx % 512;
        int d = rem >> 5, q = rem & 31;
        *(float4*)&wL[e][d][q * 4] = v;
    }
#pragma unroll
    for (int p = 0; p < 3; ++p) {    // T tiles: 3*64*16 = 768 f4
        int idx = t + p * 256;
        int e = idx >> 8, rem = idx & 255;
        int r = rem >> 2, q = rem & 3;
        float4 v = *(const float4*)(T1 + ((size_t)(b * 3 + e) * 384 + m0 + r) * 16 + q * 4);
        tL[e][r][q*4+0] = v.x; tL[e][r][q*4+1] = v.y; tL[e][r][q*4+2] = v.z; tL[e][r][q*4+3] = v.w;
    }
    __syncthreads();
    int tx = t & 31;                 // cols c = tx + 32j, j<4
    int ty = t >> 5;                 // rows r = ty + 8i, i<8
    float tot[8][4] = {};
#pragma unroll
    for (int e = 0; e < 3; ++e) {
        float acc[8][4] = {};
#pragma unroll
        for (int d = 0; d < 16; ++d) {
            float a[8], w[4];
#pragma unroll
            for (int i = 0; i < 8; ++i) a[i] = tL[e][ty + 8 * i][d];
#pragma unroll
            for (int j = 0; j < 4; ++j) w[j] = wL[e][d][tx + 32 * j];
#pragma unroll
            for (int i = 0; i < 8; ++i)
#pragma unroll
                for (int j = 0; j < 4; ++j)
                    acc[i][j] = fmaf(a[i], w[j], acc[i][j]);
        }
#pragma unroll
        for (int i = 0; i < 8; ++i)
#pragma unroll
            for (int j = 0; j < 4; ++j)
                tot[i][j] += fmaxf(acc[i][j], 0.f);
    }
    float* out = h1 + (size_t)rt * 64 * 128;
#pragma unroll
    for (int i = 0; i < 8; ++i)
#pragma unroll
        for (int j = 0; j < 4; ++j)
            out[(ty + 8 * i) * 128 + tx + 32 * j] = tot[i][j];
}

// ---------------- kernel 3: S_t hi/lo fp16 = (h[b] @ W[e])^T  (64x128 tile, K=128) ----------------
// Output layout: S_t[b,e][n][k] (feature-major, node-contiguous), hi plane + residual*2048 plane.
__global__ __launch_bounds__(256) void k_support(const float* __restrict__ hin,
        const float* __restrict__ W, _Float16* __restrict__ Sh, _Float16* __restrict__ Sl) {
    int rt = blockIdx.x, e = blockIdx.y;
    int b = rt / 6, n0 = (rt % 6) * 64;   // n0 = node-index tile base (the k of the adj-gemm)
    const float* Hp = hin + (size_t)rt * 64 * 128;
    const float* Wp = W + (size_t)e * 128 * 128;
    __shared__ float aT[32][68];    // [k][row]
    __shared__ float bT[32][132];   // [k][col]
    int t = threadIdx.x;
    int tx = t & 15;                // cols {4tx..4tx+3, 64+4tx..}
    int ty = t >> 4;                // rows 4ty..4ty+3
    float acc[4][8] = {};
    for (int k0 = 0; k0 < 128; k0 += 32) {
        __syncthreads();
#pragma unroll
        for (int p = 0; p < 2; ++p) {          // h tile 64x32 transposed (512 f4)
            int idx = t + p * 256;
            int r = idx >> 3, q = idx & 7;
            float4 v = *(const float4*)(Hp + (size_t)r * 128 + k0 + q * 4);
            aT[q*4+0][r] = v.x; aT[q*4+1][r] = v.y; aT[q*4+2][r] = v.z; aT[q*4+3][r] = v.w;
        }
#pragma unroll
        for (int p = 0; p < 4; ++p) {          // W tile 32x128 (1024 f4)
            int idx = t + p * 256;
            int r = idx >> 5, q = idx & 31;
            *(float4*)&bT[r][q * 4] = *(const float4*)(Wp + (size_t)(k0 + r) * 128 + q * 4);
        }
        __syncthreads();
#pragma unroll
        for (int k = 0; k < 32; ++k) {
            float4 av = *(const float4*)&aT[k][4 * ty];
            float4 b0 = *(const float4*)&bT[k][4 * tx];
            float4 b1 = *(const float4*)&bT[k][64 + 4 * tx];
            float a[4] = {av.x, av.y, av.z, av.w};
            float bb[8] = {b0.x, b0.y, b0.z, b0.w, b1.x, b1.y, b1.z, b1.w};
#pragma unroll
            for (int i = 0; i < 4; ++i)
#pragma unroll
                for (int j = 0; j < 8; ++j)
                    acc[i][j] = fmaf(a[i], bb[j], acc[i][j]);
        }
    }
    // epilogue: split to fp16 hi + scaled residual, store transposed: S_t[n][n0+4ty .. +3]
    size_t base = (size_t)(b * 3 + e) * 128 * 384;
#pragma unroll
    for (int j = 0; j < 8; ++j) {
        int n = (j < 4) ? (4 * tx + j) : (64 + 4 * tx + j - 4);
        h4v hh, ll;
#pragma unroll
        for (int i = 0; i < 4; ++i) {
            float v = acc[i][j];
            _Float16 h = (_Float16)v;
            hh[i] = h;
            ll[i] = (_Float16)((v - (float)h) * SPLIT_SCALE);
        }
        size_t off = base + (size_t)n * 384 + n0 + 4 * ty;
        *(h4v*)(Sh + off) = hh;
        *(h4v*)(Sl + off) = ll;
    }
}

// ---------------- kernel 4: out[b] += relu?(adj[b,e] @ S[b,e]) via scaled-split fp16 MFMA ----------------
// 96x128 block tile, grid (4 mt, 3 e, 64 b) = 768 blocks = 3.0/CU. 4 waves as 2x2 grid
// of 48x64 wave tiles (3x4 MFMA subtiles of 16x16, K=32 per chunk).
// acc0 = ah*Sh; acc1 = ah*Sl' + al'*Sh (scale 2^11); result = acc0 + acc1/2048. (ll dropped)
template <int RELU>
__global__ __launch_bounds__(256, 3) void k_adj_mfma(const float* __restrict__ adj,
        const _Float16* __restrict__ Sh, const _Float16* __restrict__ Sl,
        float* __restrict__ out) {
    int mt = blockIdx.x, e = blockIdx.y, b = blockIdx.z;
    const float* A = adj + (size_t)(b * 3 + e) * ADJ_BE + (size_t)mt * 96 * 384;
    const _Float16* Bh = Sh + (size_t)(b * 3 + e) * 128 * 384;
    const _Float16* Bl = Sl + (size_t)(b * 3 + e) * 128 * 384;
    float* O = out + ((size_t)b * 384 + mt * 96) * 128;

    // fragment-linear LDS: [plane][subtile][quad(k8)][lane16] -> 8 f16 (16 B slots)
    __shared__ _Float16 Af[2][6][4][16][8];   // 12 KB  (96 rows x 32 k)
    __shared__ _Float16 Bf[2][8][4][16][8];   // 16 KB  (128 cols x 32 k)

    int t = threadIdx.x;
    int wave = t >> 6, lane = t & 63;
    int l16 = lane & 15, quad = lane >> 4;
    int wm = wave >> 1, wn = wave & 1;        // wave tile: rows 48*wm.., cols 64*wn..

    f32x4 acc0[3][4], acc1[3][4];
#pragma unroll
    for (int i = 0; i < 3; ++i)
#pragma unroll
        for (int j = 0; j < 4; ++j) {
            acc0[i][j] = f32x4{0.f, 0.f, 0.f, 0.f};
            acc1[i][j] = f32x4{0.f, 0.f, 0.f, 0.f};
        }

    for (int k0 = 0; k0 < 384; k0 += 32) {
        __syncthreads();
        // stage A: 96x32 fp32 -> hi + scaled-residual fp16 frags. 768 float4 chunks, 3/thread.
#pragma unroll
        for (int p = 0; p < 3; ++p) {
            int idx = t + p * 256;            // 0..767
            int r = idx >> 3, q4 = idx & 7;   // row, 4-float k-group
            float4 v = *(const float4*)(A + (size_t)r * 384 + k0 + 4 * q4);
            h4v hh, ll;
            float vv[4] = {v.x, v.y, v.z, v.w};
#pragma unroll
            for (int c = 0; c < 4; ++c) {
                _Float16 h = (_Float16)vv[c];
                hh[c] = h;
                ll[c] = (_Float16)((vv[c] - (float)h) * SPLIT_SCALE);
            }
            *(h4v*)&Af[0][r >> 4][q4 >> 1][r & 15][(q4 & 1) * 4] = hh;
            *(h4v*)&Af[1][r >> 4][q4 >> 1][r & 15][(q4 & 1) * 4] = ll;
        }
        // stage B: 128 cols x 32 k per plane, 16-B chunks, 2/thread/plane
#pragma unroll
        for (int p = 0; p < 2; ++p) {
            int idx = t + p * 256;            // 0..511
            int n = idx >> 2, q8 = idx & 3;
            size_t off = (size_t)n * 384 + k0 + 8 * q8;
            *(h8v*)&Bf[0][n >> 4][q8][n & 15][0] = *(const h8v*)(Bh + off);
            *(h8v*)&Bf[1][n >> 4][q8][n & 15][0] = *(const h8v*)(Bl + off);
        }
        __syncthreads();
        // A fragments (reused across j)
        h8v a_h[3], a_l[3];
#pragma unroll
        for (int i = 0; i < 3; ++i) {
            a_h[i] = *(const h8v*)&Af[0][3 * wm + i][quad][l16][0];
            a_l[i] = *(const h8v*)&Af[1][3 * wm + i][quad][l16][0];
        }
#pragma unroll
        for (int j = 0; j < 4; ++j) {
            h8v b_h = *(const h8v*)&Bf[0][4 * wn + j][quad][l16][0];
            h8v b_l = *(const h8v*)&Bf[1][4 * wn + j][quad][l16][0];
#pragma unroll
            for (int i = 0; i < 3; ++i) {
                acc0[i][j] = __builtin_amdgcn_mfma_f32_16x16x32_f16(a_h[i], b_h, acc0[i][j], 0, 0, 0);
                acc1[i][j] = __builtin_amdgcn_mfma_f32_16x16x32_f16(a_h[i], b_l, acc1[i][j], 0, 0, 0);
                acc1[i][j] = __builtin_amdgcn_mfma_f32_16x16x32_f16(a_l[i], b_h, acc1[i][j], 0, 0, 0);
            }
        }
    }
    // epilogue: C/D layout col=lane&15, row=quad*4+reg. Contiguous 16-lane atomics.
#pragma unroll
    for (int i = 0; i < 3; ++i) {
        int r0 = 48 * wm + 16 * i + quad * 4;
#pragma unroll
        for (int j = 0; j < 4; ++j) {
            int gc = 64 * wn + 16 * j + l16;
#pragma unroll
            for (int reg = 0; reg < 4; ++reg) {
                float v = fmaf(acc1[i][j][reg], INV_SPLIT_SCALE, acc0[i][j][reg]);
                if (RELU) v = fmaxf(v, 0.f);
                atomicAdd(O + (size_t)(r0 + reg) * 128 + gc, v);
            }
        }
    }
}

// ---------------- zero helper ----------------
__global__ void k_zero(float* __restrict__ p, int n4) {
    int i = blockIdx.x * blockDim.x + threadIdx.x;
    if (i < n4) ((float4*)p)[i] = float4{0.f, 0.f, 0.f, 0.f};
}

// ---------------- kernel 5: fused head ----------------
__global__ __launch_bounds__(256) void k_head(const float* __restrict__ h3,
        const float* __restrict__ st_w1, const float* __restrict__ st_b1,
        const float* __restrict__ st_w2, const float* __restrict__ st_b2,
        const float* __restrict__ rescale_w, float* __restrict__ out) {
    __shared__ float hL[64][132];
    __shared__ float w1L[64][132];
    __shared__ float ytL[64][68];
    __shared__ float w2L[32][68];
    __shared__ float b1L[64], b2L[32];
    int t = threadIdx.x;
    int r0 = blockIdx.x * 64;
#pragma unroll
    for (int p = 0; p < 8; ++p) {   // h rows 64x128 = 2048 f4
        int idx = t + p * 256;
        int r = idx >> 5, q = idx & 31;
        *(float4*)&hL[r][q * 4] = *(const float4*)(h3 + (size_t)(r0 + r) * 128 + q * 4);
    }
#pragma unroll
    for (int p = 0; p < 8; ++p) {   // w1 64x128
        int idx = t + p * 256;
        int r = idx >> 5, q = idx & 31;
        *(float4*)&w1L[r][q * 4] = *(const float4*)(st_w1 + (size_t)r * 128 + q * 4);
    }
#pragma unroll
    for (int p = 0; p < 2; ++p) {   // w2 32x64 = 512 f4
        int idx = t + p * 256;
        int r = idx >> 4, q = idx & 15;
        *(float4*)&w2L[r][q * 4] = *(const float4*)(st_w2 + (size_t)r * 64 + q * 4);
    }
    if (t < 64) b1L[t] = st_b1[t];
    else if (t < 96) b2L[t - 64] = st_b2[t - 64];
    __syncthreads();
    // phase 1: y = h @ w1^T + b1, tanh
    int tx = t & 15, ty = t >> 4;
    float acc[4][4] = {};
    for (int d = 0; d < 128; ++d) {
        float a[4], w[4];
#pragma unroll
        for (int i = 0; i < 4; ++i) a[i] = hL[ty + 16 * i][d];
#pragma unroll
        for (int j = 0; j < 4; ++j) w[j] = w1L[tx + 16 * j][d];
#pragma unroll
        for (int i = 0; i < 4; ++i)
#pragma unroll
            for (int j = 0; j < 4; ++j)
                acc[i][j] = fmaf(a[i], w[j], acc[i][j]);
    }
#pragma unroll
    for (int i = 0; i < 4; ++i)
#pragma unroll
        for (int j = 0; j < 4; ++j)
            ytL[ty + 16 * i][tx + 16 * j] = tanhf(acc[i][j] + b1L[tx + 16 * j]);
    __syncthreads();
    // phase 2: z = yt @ w2^T + b2; split into s (tanh*exp(rescale)) and t
    int tx8 = t & 7, ty32 = t >> 3;
    float acc2[2][4] = {};
    for (int d = 0; d < 64; ++d) {
        float a[2], w[4];
#pragma unroll
        for (int i = 0; i < 2; ++i) a[i] = ytL[ty32 + 32 * i][d];
#pragma unroll
        for (int j = 0; j < 4; ++j) w[j] = w2L[tx8 + 8 * j][d];
#pragma unroll
        for (int i = 0; i < 2; ++i)
#pragma unroll
            for (int j = 0; j < 4; ++j)
                acc2[i][j] = fmaf(a[i], w[j], acc2[i][j]);
    }
    float er = expf(rescale_w[0]);
#pragma unroll
    for (int i = 0; i < 2; ++i) {
        int r = r0 + ty32 + 32 * i;
#pragma unroll
        for (int j = 0; j < 4; ++j) {
            int c = tx8 + 8 * j;
            float z = acc2[i][j] + b2L[c];
            if (c < 16) out[(size_t)r * 16 + c] = er * tanhf(z);
            else        out[(size_t)(ROWS + r) * 16 + (c - 16)] = z;
        }
    }
}

extern "C" void kernel_launch(void* const* d_in, const int* in_sizes, int n_in,
                              void* d_out, int out_size, void* d_ws, size_t ws_size,
                              hipStream_t stream) {
    const float* x     = (const float*)d_in[0];
    const float* adj   = (const float*)d_in[1];
    const float* emb_w = (const float*)d_in[2];
    const float* gc1   = (const float*)d_in[3];
    const float* gc2   = (const float*)d_in[4];
    const float* gc3   = (const float*)d_in[5];
    const float* st_w1 = (const float*)d_in[6];
    const float* st_b1 = (const float*)d_in[7];
    const float* st_w2 = (const float*)d_in[8];
    const float* st_b2 = (const float*)d_in[9];
    const float* resc  = (const float*)d_in[10];
    float* out = (float*)d_out;
    float* ws  = (float*)d_ws;

    // workspace layout: T1 4.7MB | hA 12.6MB | hB 12.6MB | Sh 18.9MB | Sl 18.9MB = 67.7MB
    float* T1 = ws;                          // 1179648 f
    float* hA = T1 + 1179648;                // 3145728 f (h1, later h3)
    float* hB = hA + 3145728;                // 3145728 f (h2)
    _Float16* Sh = (_Float16*)(hB + 3145728);  // 9437184 halves
    _Float16* Sl = Sh + 9437184;               // 9437184 halves

    // layer 1 (reassociated): T = adj@(x@emb^T), h1 = sum_e relu(T@W1)
    k_embed_adj<<<dim3(2, 3, 64), 256, 0, stream>>>(x, emb_w, adj, T1);
    k_l1s2<<<384, 256, 0, stream>>>(T1, gc1, hA);
    // layer 2
    k_support<<<dim3(384, 3), 256, 0, stream>>>(hA, gc2, Sh, Sl);
    k_zero<<<3072, 256, 0, stream>>>(hB, 786432);
    k_adj_mfma<1><<<dim3(4, 3, 64), 256, 0, stream>>>(adj, Sh, Sl, hB);
    // layer 3 (no relu)
    k_support<<<dim3(384, 3), 256, 0, stream>>>(hB, gc3, Sh, Sl);
    k_zero<<<3072, 256, 0, stream>>>(hA, 786432);
    k_adj_mfma<0><<<dim3(4, 3, 64), 256, 0, stream>>>(adj, Sh, Sl, hA);
    // head
    k_head<<<384, 256, 0, stream>>>(hA, st_w1, st_b1, st_w2, st_b2, resc, out);
}